// Round 1
// baseline (1927.829 us; speedup 1.0000x reference)
//
#include <hip/hip_runtime.h>
#include <math.h>

// Elman RNN, fused persistent kernel.
// x: (S,B,I) f32; W1: (H,I); b1: (H); W2: (H,H); b2: (H)
// out: h_seq (S,B,H) f32 followed by h_last (1,B,H) f32.
//
// Each batch row's recurrence is independent -> one block per batch row,
// no grid sync. Thread j computes output unit j. W1/W2 rows in registers,
// h double-buffered in LDS (broadcast float4 reads), x prefetched 1 step.

#define S_LEN 2048
#define B_SZ  512
#define I_SZ  64
#define H_SZ  128

__global__ __launch_bounds__(H_SZ, 1) void rnn_fused(
    const float* __restrict__ x,
    const float* __restrict__ W1,
    const float* __restrict__ b1,
    const float* __restrict__ W2,
    const float* __restrict__ b2,
    float* __restrict__ out)
{
    const int b = blockIdx.x;    // batch row 0..511
    const int j = threadIdx.x;   // output unit 0..127

    __shared__ float hbuf[2][H_SZ];
    __shared__ float xbuf[2][I_SZ];

    // ---- weights into registers (row j of W2 and W1) ----
    float w2r[H_SZ];
    #pragma unroll
    for (int k = 0; k < H_SZ; ++k) w2r[k] = W2[j * H_SZ + k];
    float w1r[I_SZ];
    #pragma unroll
    for (int k = 0; k < I_SZ; ++k) w1r[k] = W1[j * I_SZ + k];
    const float zb = b1[j] + b2[j];

    // h_0 = 0; prefetch x for s=0
    hbuf[0][j] = 0.0f;
    const float* xrow = x + (size_t)b * I_SZ + j;  // element j of row b, step 0
    if (j < I_SZ) xbuf[0][j] = xrow[0];
    __syncthreads();

    float* optr = out + (size_t)b * H_SZ + j;      // h_seq element, step 0
    float t = 0.0f;

    for (int s = 0; s < S_LEN; ++s) {
        const int cur = s & 1;

        // ---- prefetch x for step s+1 (clamped; last-step value unused) ----
        float xpre = 0.0f;
        const int sp = (s + 1 < S_LEN) ? (s + 1) : s;
        if (j < I_SZ) xpre = xrow[(size_t)sp * (B_SZ * I_SZ)];

        // ---- dot products: acc = zb + W2[j,:]·h + W1[j,:]·x_t ----
        float acc0 = zb, acc1 = 0.0f, acc2 = 0.0f, acc3 = 0.0f;

        const float4* hv = (const float4*)hbuf[cur];
        #pragma unroll
        for (int kb = 0; kb < H_SZ / 4; ++kb) {
            float4 q = hv[kb];                  // broadcast: all lanes same addr
            acc0 += w2r[4 * kb + 0] * q.x;
            acc1 += w2r[4 * kb + 1] * q.y;
            acc2 += w2r[4 * kb + 2] * q.z;
            acc3 += w2r[4 * kb + 3] * q.w;
        }
        const float4* xv = (const float4*)xbuf[cur];
        #pragma unroll
        for (int kb = 0; kb < I_SZ / 4; ++kb) {
            float4 q = xv[kb];
            acc0 += w1r[4 * kb + 0] * q.x;
            acc1 += w1r[4 * kb + 1] * q.y;
            acc2 += w1r[4 * kb + 2] * q.z;
            acc3 += w1r[4 * kb + 3] * q.w;
        }
        float a = (acc0 + acc1) + (acc2 + acc3);

        // tanh(a) = 1 - 2/(1+exp(2a)); saturates correctly for |a| large
        t = 1.0f - 2.0f / (1.0f + __expf(2.0f * a));

        // ---- publish state, write output, prefetch -> LDS ----
        hbuf[cur ^ 1][j] = t;
        if (j < I_SZ) xbuf[cur ^ 1][j] = xpre;
        optr[(size_t)s * (B_SZ * H_SZ)] = t;

        __syncthreads();
    }

    // h_last (register `t` holds step S-1's value for unit j)
    out[(size_t)S_LEN * B_SZ * H_SZ + (size_t)b * H_SZ + j] = t;
}

extern "C" void kernel_launch(void* const* d_in, const int* in_sizes, int n_in,
                              void* d_out, int out_size, void* d_ws, size_t ws_size,
                              hipStream_t stream) {
    const float* x  = (const float*)d_in[0];
    const float* W1 = (const float*)d_in[1];
    const float* b1 = (const float*)d_in[2];
    const float* W2 = (const float*)d_in[3];
    const float* b2 = (const float*)d_in[4];
    float* out = (float*)d_out;

    rnn_fused<<<dim3(B_SZ), dim3(H_SZ), 0, stream>>>(x, W1, b1, W2, b2, out);
}

// Round 2
// 1731.263 us; speedup vs baseline: 1.1135x; 1.1135x over previous
//
#include <hip/hip_runtime.h>
#include <math.h>

// Elman RNN, fused persistent kernel, 4-way K-split.
// x: (S,B,I) f32; W1: (H,I); b1: (H); W2: (H,H); b2: (H)
// out: h_seq (S,B,H) f32 followed by h_last (1,B,H) f32.
//
// One block per batch row (recurrences independent -> no grid sync).
// Block = 512 threads = 8 waves. Thread (q = tid>>7, j = tid&127) computes
// a quarter of unit j's dot product: 32 W2-terms + 16 W1-terms = 48 FMAs,
// so only 48 weight floats per thread (register-resident; round-1's 192-float
// arrays were NOT kept in VGPRs -> VGPR_Count 116 < 192, hence the 2.3x
// VALU overshoot). Partials reduced through LDS.
//
// Grid 512 -> 2 blocks/CU -> 4 waves/SIMD; the two blocks' barriers are
// independent, so fence phases of one block overlap FMA phases of the other.
//
// Barriers are raw s_barrier + lgkmcnt(0) only: __syncthreads() would emit
// s_waitcnt vmcnt(0) and drain the per-step h_seq global store inside the
// serial loop (round-1's hidden ~1000 cyc/step stall).

#define S_LEN 2048
#define B_SZ  512
#define I_SZ  64
#define H_SZ  128
#define NQ    4
#define BLK   (H_SZ * NQ)   // 512

#define LDS_BARRIER()                                        \
    asm volatile("s_waitcnt lgkmcnt(0)" ::: "memory");       \
    __builtin_amdgcn_s_barrier();                            \
    asm volatile("" ::: "memory")

__global__ __launch_bounds__(BLK, 4) void rnn_fused(
    const float* __restrict__ x,
    const float* __restrict__ W1,
    const float* __restrict__ b1,
    const float* __restrict__ W2,
    const float* __restrict__ b2,
    float* __restrict__ out)
{
    const int tid = threadIdx.x;
    const int j   = tid & (H_SZ - 1);   // output unit 0..127
    const int q   = tid >> 7;           // K-quarter 0..3
    const int b   = blockIdx.x;         // batch row

    __shared__ float hbuf[2][H_SZ];     // hidden state, double-buffered
    __shared__ float xbuf[2][I_SZ];     // x_t staging, double-buffered
    __shared__ float part[NQ][H_SZ];    // partial dot products

    // ---- weights into registers: quarter q of rows j ----
    float w2[32];
    #pragma unroll
    for (int i = 0; i < 32; ++i) w2[i] = W2[j * H_SZ + q * 32 + i];
    float w1[16];
    #pragma unroll
    for (int i = 0; i < 16; ++i) w1[i] = W1[j * I_SZ + q * 16 + i];
    const float zb = b1[j] + b2[j];

    // ---- init: h0 = 0, stage x(0), prefetch x(1) into register ----
    if (tid < H_SZ) hbuf[0][tid] = 0.0f;
    if (tid < I_SZ) xbuf[0][tid] = x[(size_t)b * I_SZ + tid];

    const int jx = tid - (BLK - 64);    // loader lane for wave 7 (tid>=448)
    float xp = 0.0f;                    // holds x(s+1) at top of iteration s
    if (tid >= BLK - 64)
        xp = x[((size_t)1 * B_SZ + b) * I_SZ + jx];

    __syncthreads();                    // once, outside the loop: fine

    float t = 0.0f;

    for (int s = 0; s < S_LEN; ++s) {
        const int cur = s & 1;
        const int nxt = cur ^ 1;

        // ---- compute phase: 48 FMAs on this thread's K-quarter ----
        float acc0 = 0.0f, acc1 = 0.0f, acc2 = 0.0f, acc3 = 0.0f;

        const float4* hv = (const float4*)&hbuf[cur][q * 32];  // broadcast
        #pragma unroll
        for (int kb = 0; kb < 8; ++kb) {
            float4 hq = hv[kb];
            acc0 += w2[4 * kb + 0] * hq.x;
            acc1 += w2[4 * kb + 1] * hq.y;
            acc2 += w2[4 * kb + 2] * hq.z;
            acc3 += w2[4 * kb + 3] * hq.w;
        }
        const float4* xv = (const float4*)&xbuf[cur][q * 16];  // broadcast
        #pragma unroll
        for (int kb = 0; kb < 4; ++kb) {
            float4 xq = xv[kb];
            acc0 += w1[4 * kb + 0] * xq.x;
            acc1 += w1[4 * kb + 1] * xq.y;
            acc2 += w1[4 * kb + 2] * xq.z;
            acc3 += w1[4 * kb + 3] * xq.w;
        }
        part[q][j] = (acc0 + acc1) + (acc2 + acc3);

        // ---- x prefetch pipeline (wave 7 only; uniform branch) ----
        if (tid >= BLK - 64) {
            xbuf[nxt][jx] = xp;                         // x(s+1) -> LDS
            const int sp = (s + 2 < S_LEN) ? (s + 2) : (S_LEN - 1);
            xp = x[((size_t)sp * B_SZ + b) * I_SZ + jx]; // issue x(s+2)
        }

        LDS_BARRIER();

        // ---- finalize phase: all threads reduce unit j (redundant x4) ----
        float a = ((part[0][j] + part[1][j]) + (part[2][j] + part[3][j])) + zb;
        // tanh(a) = 1 - 2/(1 + exp(2a)); saturates correctly at +-inf
        t = 1.0f - 2.0f * __builtin_amdgcn_rcpf(1.0f + __expf(2.0f * a));

        if (q == 0) {
            hbuf[nxt][j] = t;                           // publish h(s+1)
            out[(size_t)s * (B_SZ * H_SZ) + (size_t)b * H_SZ + j] = t;
        }

        LDS_BARRIER();
    }

    // h_last
    if (q == 0)
        out[(size_t)S_LEN * (B_SZ * H_SZ) + (size_t)b * H_SZ + j] = t;
}

extern "C" void kernel_launch(void* const* d_in, const int* in_sizes, int n_in,
                              void* d_out, int out_size, void* d_ws, size_t ws_size,
                              hipStream_t stream) {
    const float* x  = (const float*)d_in[0];
    const float* W1 = (const float*)d_in[1];
    const float* b1 = (const float*)d_in[2];
    const float* W2 = (const float*)d_in[3];
    const float* b2 = (const float*)d_in[4];
    float* out = (float*)d_out;

    rnn_fused<<<dim3(B_SZ), dim3(BLK), 0, stream>>>(x, W1, b1, W2, b2, out);
}

// Round 3
// 1289.643 us; speedup vs baseline: 1.4949x; 1.3424x over previous
//
#include <hip/hip_runtime.h>
#include <math.h>

// Elman RNN, fused persistent kernel, 4-way K-split, register-pinned weights.
// x: (S,B,I) f32; W1: (H,I); b1: (H); W2: (H,H); b2: (H)
// out: h_seq (S,B,H) f32 followed by h_last (1,B,H) f32.
//
// One block per batch row; block = 512 threads = 8 waves. Thread (q=tid>>7,
// j=tid&127) computes a quarter of unit j's dot product (32 W2 + 16 W1 FMAs).
// Partials reduced through LDS by the q==0 waves only (wave-uniform branch).
//
// Round-2 lesson: the compiler sank the weight loads into the loop
// (VGPR_Count=44 < 48 weights) -> 3x VALU issue inflation. The empty
// "+v" asm below makes each weight an opaque register-resident value the
// compiler cannot rematerialize or sink.
//
// Barriers are raw s_barrier + lgkmcnt(0): __syncthreads() would emit
// s_waitcnt vmcnt(0) and drain the per-step h_seq global store in-loop.

#define S_LEN 2048
#define B_SZ  512
#define I_SZ  64
#define H_SZ  128
#define NQ    4
#define BLK   (H_SZ * NQ)   // 512

#define LDS_BARRIER()                                        \
    asm volatile("s_waitcnt lgkmcnt(0)" ::: "memory");       \
    __builtin_amdgcn_s_barrier();                            \
    asm volatile("" ::: "memory")

__global__ __launch_bounds__(BLK, 4) void rnn_fused(
    const float* __restrict__ x,
    const float* __restrict__ W1,
    const float* __restrict__ b1,
    const float* __restrict__ W2,
    const float* __restrict__ b2,
    float* __restrict__ out)
{
    const int tid = threadIdx.x;
    const int j   = tid & (H_SZ - 1);   // output unit 0..127
    const int q   = tid >> 7;           // K-quarter 0..3 (wave-uniform)
    const int b   = blockIdx.x;         // batch row

    __shared__ float hbuf[2][H_SZ];     // hidden state, double-buffered
    __shared__ float xbuf[2][I_SZ];     // x_t staging, double-buffered
    __shared__ float part[NQ][H_SZ];    // partial dot products

    // ---- weights into registers: quarter q of row j; PIN in VGPRs ----
    float w2[32];
    #pragma unroll
    for (int i = 0; i < 32; ++i) {
        w2[i] = W2[j * H_SZ + q * 32 + i];
        asm volatile("" : "+v"(w2[i]));          // opaque: no remat/sink
    }
    float w1[16];
    #pragma unroll
    for (int i = 0; i < 16; ++i) {
        w1[i] = W1[j * I_SZ + q * 16 + i];
        asm volatile("" : "+v"(w1[i]));
    }
    const float zb = b1[j] + b2[j];

    // ---- init: h0 = 0, stage x(0), prefetch x(1) into register ----
    if (tid < H_SZ) hbuf[0][tid] = 0.0f;
    if (tid < I_SZ) xbuf[0][tid] = x[(size_t)b * I_SZ + tid];

    const int jx = tid - (BLK - 64);    // loader lane id for wave 7
    float xp = 0.0f;                    // holds x(s+1) at top of iteration s
    if (tid >= BLK - 64)
        xp = x[((size_t)1 * B_SZ + b) * I_SZ + jx];

    __syncthreads();                    // once, outside the loop: fine

    float t = 0.0f;
    float* optr = out + (size_t)b * H_SZ + j;   // q0 waves' h_seq pointer

    for (int s = 0; s < S_LEN; ++s) {
        const int cur = s & 1;
        const int nxt = cur ^ 1;

        // ---- compute phase: 48 FMAs on this thread's K-quarter ----
        float acc0 = 0.0f, acc1 = 0.0f, acc2 = 0.0f, acc3 = 0.0f;

        const float4* hv = (const float4*)&hbuf[cur][q * 32];  // broadcast
        #pragma unroll
        for (int kb = 0; kb < 8; ++kb) {
            float4 hq = hv[kb];
            acc0 += w2[4 * kb + 0] * hq.x;
            acc1 += w2[4 * kb + 1] * hq.y;
            acc2 += w2[4 * kb + 2] * hq.z;
            acc3 += w2[4 * kb + 3] * hq.w;
        }
        const float4* xv = (const float4*)&xbuf[cur][q * 16];  // broadcast
        #pragma unroll
        for (int kb = 0; kb < 4; ++kb) {
            float4 xq = xv[kb];
            acc0 += w1[4 * kb + 0] * xq.x;
            acc1 += w1[4 * kb + 1] * xq.y;
            acc2 += w1[4 * kb + 2] * xq.z;
            acc3 += w1[4 * kb + 3] * xq.w;
        }
        part[q][j] = (acc0 + acc1) + (acc2 + acc3);

        // ---- x prefetch pipeline (wave 7 only; uniform branch) ----
        if (tid >= BLK - 64) {
            xbuf[nxt][jx] = xp;                          // x(s+1) -> LDS
            const int sp = (s + 2 < S_LEN) ? (s + 2) : (S_LEN - 1);
            xp = x[((size_t)sp * B_SZ + b) * I_SZ + jx]; // issue x(s+2)
        }

        LDS_BARRIER();

        // ---- finalize: q==0 waves only (cover all 128 units) ----
        if (q == 0) {
            float a = ((part[0][j] + part[1][j]) +
                       (part[2][j] + part[3][j])) + zb;
            // tanh(a) = 1 - 2/(1 + exp(2a)); saturates correctly at +-inf
            t = 1.0f - 2.0f * __builtin_amdgcn_rcpf(1.0f + __expf(2.0f * a));
            hbuf[nxt][j] = t;                            // publish h(s+1)
            optr[(size_t)s * (B_SZ * H_SZ)] = t;         // h_seq store
        }

        LDS_BARRIER();
    }

    // h_last
    if (q == 0)
        out[(size_t)S_LEN * (B_SZ * H_SZ) + (size_t)b * H_SZ + j] = t;
}

extern "C" void kernel_launch(void* const* d_in, const int* in_sizes, int n_in,
                              void* d_out, int out_size, void* d_ws, size_t ws_size,
                              hipStream_t stream) {
    const float* x  = (const float*)d_in[0];
    const float* W1 = (const float*)d_in[1];
    const float* b1 = (const float*)d_in[2];
    const float* W2 = (const float*)d_in[3];
    const float* b2 = (const float*)d_in[4];
    float* out = (float*)d_out;

    rnn_fused<<<dim3(B_SZ), dim3(BLK), 0, stream>>>(x, W1, b1, W2, b2, out);
}